// Round 20
// baseline (89.957 us; speedup 1.0000x reference)
//
#include <hip/hip_runtime.h>

#define LOG2E 1.4426950408889634f

typedef short bf16x8 __attribute__((ext_vector_type(8)));
typedef short short4v __attribute__((ext_vector_type(4)));
typedef float f32x4 __attribute__((ext_vector_type(4)));
typedef unsigned u32x4 __attribute__((ext_vector_type(4)));
typedef unsigned __attribute__((address_space(1))) u32g;
typedef unsigned __attribute__((address_space(3))) u32l;

#define MFMA16(a, b, c) __builtin_amdgcn_mfma_f32_16x16x32_bf16((a), (b), (c), 0, 0, 0)

__device__ __forceinline__ short f2bf(float f) {
  unsigned u = __builtin_bit_cast(unsigned, f);
  u += 0x7FFFu + ((u >> 16) & 1u);
  return (short)(u >> 16);
}

__device__ __forceinline__ unsigned cvtpk(float lo, float hi) {
  unsigned r;
  asm("v_cvt_pk_bf16_f32 %0, %1, %2" : "=v"(r) : "v"(lo), "v"(hi));
  return r;
}

__device__ __forceinline__ void g2l16(void* lds, const void* g) {
  __builtin_amdgcn_global_load_lds((u32g*)const_cast<void*>(g), (u32l*)lds, 16, 0, 0);
}

// ---------------------------------------------------------------------------
// GroupNorm stats: per (b, group) mean/rstd -> per-channel affine
//   sa[b][c] = gamma[c]*rstd,  sb[b][c] = beta[c] - mean*sa
// ---------------------------------------------------------------------------
__global__ __launch_bounds__(256) void gn_stats(const float* __restrict__ x,
                                                const float* __restrict__ gamma,
                                                const float* __restrict__ beta,
                                                float* __restrict__ sa,
                                                float* __restrict__ sb) {
  __shared__ float red[8];
  const int bg = blockIdx.x;
  const int b = bg >> 5, g = bg & 31;
  const int t = threadIdx.x;
  const float4* gx4 = (const float4*)(x + (size_t)(b * 512 + g * 16) * 1024);
  float s1 = 0.f, s2 = 0.f;
  for (int i = 0; i < 16; ++i) {
    float4 v = gx4[t + 256 * i];
    s1 += (v.x + v.y) + (v.z + v.w);
    s2 += (v.x * v.x + v.y * v.y) + (v.z * v.z + v.w * v.w);
  }
  for (int m = 1; m < 64; m <<= 1) {
    s1 += __shfl_xor(s1, m);
    s2 += __shfl_xor(s2, m);
  }
  if ((t & 63) == 0) {
    red[(t >> 6) * 2] = s1;
    red[(t >> 6) * 2 + 1] = s2;
  }
  __syncthreads();
  s1 = (red[0] + red[2]) + (red[4] + red[6]);
  s2 = (red[1] + red[3]) + (red[5] + red[7]);
  const float mean = s1 * (1.f / 16384.f);
  const float var = s2 * (1.f / 16384.f) - mean * mean;
  const float rstd = rsqrtf(var + 1e-6f);
  if (t < 16) {
    const int c = g * 16 + t;
    const float ga = gamma[c] * rstd;
    sa[b * 512 + c] = ga;
    sb[b * 512 + c] = fmaf(-mean, ga, beta[c]);
  }
}

// ---------------------------------------------------------------------------
__global__ __launch_bounds__(256) void f2bf2_kernel(const float* __restrict__ s1,
                                                    short* __restrict__ d1, int n1,
                                                    const float* __restrict__ s2,
                                                    short* __restrict__ d2) {
  int i = blockIdx.x * 256 + threadIdx.x;
  const float* s = (i < n1) ? s1 : s2;
  short* d = (i < n1) ? d1 : d2;
  int j = (i < n1) ? i : i - n1;
  float4 v = ((const float4*)s)[j];
  short4v o = {f2bf(v.x), f2bf(v.y), f2bf(v.z), f2bf(v.w)};
  *(short4v*)(d + (size_t)j * 4) = o;
}

// ---------------------------------------------------------------------------
// FUSED GroupNorm + QKV GEMM. FIXED vs R19: B chunk is cc = rg (NOT
// rg ^ ((col>>1)&3)). Derivation: the A-side chunk-XOR swizzle CANCELS on
// read (LDS[row][slot]=global[row][slot^s], read slot=rg^s -> chunk rg), so
// the MFMA pairs A's k=rg*8+e with B's k=rg*8+e; B must be built at chunk rg.
// The col-dependent permutation was sum-breaking (one-operand, non-uniform) —
// R19's absmax 0.203. Everything else (pipeline, vmcnt, race-freedom) kept.
// ---------------------------------------------------------------------------
__global__ __launch_bounds__(512, 4) void qkv_fused(const float* __restrict__ x,
                                                    const float* __restrict__ sa,
                                                    const float* __restrict__ sb,
                                                    const short* __restrict__ W,
                                                    const float* __restrict__ bias,
                                                    short* __restrict__ qbuf,
                                                    short* __restrict__ kbuf,
                                                    short* __restrict__ vtbuf) {
  __shared__ short smem[16384];  // 32 KB: 3 A-buffers; epilogue reuses all
  short (*a_sm)[4096] = (short(*)[4096])smem;
  const int t = threadIdx.x;
  const int lane = t & 63, w = t >> 6;
  const int nbase = blockIdx.x * 128;
  const int mbase = blockIdx.y * 128;
  const int b = blockIdx.z;
  const short* Asrc = W + (size_t)mbase * 512;
  const float* xb = x + (size_t)b * 524288;
  const float* sap = sa + b * 512;
  const float* sbp = sb + b * 512;

#define ASTAGE(bi, kt)                                                      \
  g2l16(&a_sm[bi][t * 8],                                                   \
        Asrc + (size_t)(t >> 2) * 512 + (kt) * 32 + (((t & 3) ^ ((t >> 3) & 3)) * 8));

  const int wm = (w >> 2) * 64, wn = (w & 3) * 32;
  const int col = lane & 15, rg = lane >> 4;
  const int cc = rg;  // B chunk MUST be rg (A-side swizzle cancels on read)
  const int n0 = wn + col, n1 = n0 + 16;

  float br0[8], br1[8];
  float4 s_a0, s_a1, s_b0, s_b1;
  bf16x8 bfr[2][2];  // [kt&1][nf]
  f32x4 acc[4][2] = {};

#define BLOADS(kt)                                                          \
  {                                                                         \
    const int kc0 = (kt) * 32 + cc * 8;                                     \
    _Pragma("unroll") for (int e = 0; e < 8; ++e) {                         \
      br0[e] = xb[(size_t)(kc0 + e) * 1024 + nbase + n0];                   \
      br1[e] = xb[(size_t)(kc0 + e) * 1024 + nbase + n1];                   \
    }                                                                       \
    s_a0 = *(const float4*)&sap[kc0];                                       \
    s_a1 = *(const float4*)&sap[kc0 + 4];                                   \
    s_b0 = *(const float4*)&sbp[kc0];                                       \
    s_b1 = *(const float4*)&sbp[kc0 + 4];                                   \
  }

#define BUILD(slot)                                                         \
  {                                                                         \
    float av[8] = {s_a0.x, s_a0.y, s_a0.z, s_a0.w, s_a1.x, s_a1.y, s_a1.z, s_a1.w}; \
    float bv[8] = {s_b0.x, s_b0.y, s_b0.z, s_b0.w, s_b1.x, s_b1.y, s_b1.z, s_b1.w}; \
    u32x4 u0, u1;                                                           \
    _Pragma("unroll") for (int p = 0; p < 4; ++p) {                         \
      u0[p] = cvtpk(fmaf(br0[2 * p], av[2 * p], bv[2 * p]),                 \
                    fmaf(br0[2 * p + 1], av[2 * p + 1], bv[2 * p + 1]));    \
      u1[p] = cvtpk(fmaf(br1[2 * p], av[2 * p], bv[2 * p]),                 \
                    fmaf(br1[2 * p + 1], av[2 * p + 1], bv[2 * p + 1]));    \
    }                                                                       \
    bfr[slot][0] = __builtin_bit_cast(bf16x8, u0);                          \
    bfr[slot][1] = __builtin_bit_cast(bf16x8, u1);                          \
  }

  // prologue
  BLOADS(0)
  ASTAGE(0, 0)
  ASTAGE(1, 1)
  asm volatile("s_waitcnt vmcnt(0)" ::: "memory");
  BUILD(0)
  __builtin_amdgcn_s_barrier();

#pragma unroll
  for (int kt = 0; kt < 16; ++kt) {
    const int cur = kt % 3;
    if (kt < 15) BLOADS(kt + 1)
    if (kt < 14) ASTAGE((kt + 2) % 3, kt + 2)

    bf16x8 af[4];
#pragma unroll
    for (int mf = 0; mf < 4; ++mf) {
      const int row = wm + mf * 16 + col;
      af[mf] = *(const bf16x8*)&a_sm[cur][row * 32 + ((rg ^ ((row >> 1) & 3)) * 8)];
    }
    __builtin_amdgcn_s_setprio(1);
#pragma unroll
    for (int mf = 0; mf < 4; ++mf)
#pragma unroll
      for (int nf = 0; nf < 2; ++nf)
        acc[mf][nf] = MFMA16(af[mf], bfr[kt & 1][nf], acc[mf][nf]);
    __builtin_amdgcn_s_setprio(0);

    if (kt < 15) {
      if (kt < 14) {
        asm volatile("s_waitcnt vmcnt(1)" ::: "memory");
      } else {
        asm volatile("s_waitcnt vmcnt(0)" ::: "memory");
      }
      BUILD((kt + 1) & 1)
    }
    __builtin_amdgcn_s_barrier();
  }
#undef ASTAGE
#undef BLOADS
#undef BUILD

  // ---- coalesced epilogue via LDS transpose (32 KB) ----
  __syncthreads();
  short* e_sm = smem;
  const int section = mbase >> 9;
  const int bh0 = b * 8 + ((mbase >> 6) & 7);

  if (section < 2) {
#pragma unroll
    for (int mf = 0; mf < 4; ++mf) {
      const int o0 = mbase + wm + mf * 16 + rg * 4;
      float b4[4];
#pragma unroll
      for (int r2 = 0; r2 < 4; ++r2) b4[r2] = bias[o0 + r2];
      const int mloc0 = wm + mf * 16 + rg * 4;
#pragma unroll
      for (int nf = 0; nf < 2; ++nf) {
        const int nn = wn + nf * 16 + col;
#pragma unroll
        for (int r2 = 0; r2 < 4; ++r2) {
          const int m = mloc0 + r2;
          e_sm[nn * 128 + (((m >> 3) ^ (nn & 7)) << 3) + (m & 7)] =
              f2bf(acc[mf][nf][r2] + b4[r2]);
        }
      }
    }
    __syncthreads();
    short* dst = (section == 0) ? qbuf : kbuf;
#pragma unroll
    for (int p = 0; p < 4; ++p) {
      const int idx = p * 512 + t;
      const int kd = idx & 7, rr = idx >> 3;
      const int hh = rr >> 7, nn = rr & 127;
      const int cm = hh * 8 + kd;
      uint4 vvv = *(const uint4*)&e_sm[nn * 128 + ((cm ^ (nn & 7)) << 3)];
      *(uint4*)&dst[((size_t)(bh0 + hh) * 1024 + nbase + nn) * 64 + kd * 8] = vvv;
    }
  } else {
#pragma unroll
    for (int mf = 0; mf < 4; ++mf) {
      const int o0 = mbase + wm + mf * 16 + rg * 4;
      float b4[4];
#pragma unroll
      for (int r2 = 0; r2 < 4; ++r2) b4[r2] = bias[o0 + r2];
      const int mloc0 = wm + mf * 16 + rg * 4;
#pragma unroll
      for (int nf = 0; nf < 2; ++nf) {
        const int nn = wn + nf * 16 + col;
        const int cn = nn >> 3;
#pragma unroll
        for (int r2 = 0; r2 < 4; ++r2) {
          const int m = mloc0 + r2;
          e_sm[m * 128 + ((cn ^ (m & 7)) << 3) + (nn & 7)] =
              f2bf(acc[mf][nf][r2] + b4[r2]);
        }
      }
    }
    __syncthreads();
#pragma unroll
    for (int p = 0; p < 4; ++p) {
      const int idx = p * 512 + t;
      const int kd = idx & 15, m = idx >> 4;
      const int hh = m >> 6, dd = m & 63;
      uint4 vvv = *(const uint4*)&e_sm[m * 128 + ((kd ^ (m & 7)) << 3)];
      *(uint4*)&vtbuf[((size_t)(bh0 + hh) * 64 + dd) * 1024 + nbase + kd * 8] = vvv;
    }
  }
}

// ---------------------------------------------------------------------------
// Flash attention (R18 — lane-local softmax, kv-split, coalesced output).
// ---------------------------------------------------------------------------
__global__ __launch_bounds__(512, 4) void attn_kernel(const short* __restrict__ qbuf,
                                                      const short* __restrict__ kbuf,
                                                      const short* __restrict__ vtbuf,
                                                      short* __restrict__ ao) {
  __shared__ char smem[65536];
  const int t = threadIdx.x, lane = t & 63, w = t >> 6;
  const int col = lane & 15, rg = lane >> 4;
  const int grp = w >> 2, wq = w & 3;
  const int tg = t & 255;
  const int bh = blockIdx.x, qt = blockIdx.y;
  const int b = bh >> 3, h = bh & 7;
  const int qbase = qt * 128 + wq * 32;

  short* kb_ = (short*)(smem + grp * 32768);
  short* vb_ = (short*)(smem + grp * 32768 + 16384);

  bf16x8 aq[2][2];
  {
    const short* qp = qbuf + ((size_t)bh * 1024 + qbase) * 64;
#pragma unroll
    for (int mf = 0; mf < 2; ++mf)
#pragma unroll
      for (int kc = 0; kc < 2; ++kc)
        aq[mf][kc] = *(const bf16x8*)&qp[(mf * 16 + col) * 64 + kc * 32 + rg * 8];
  }

  const short* kp0 = kbuf + (size_t)bh * 65536 + grp * 32768;
  const short* vp0 = vtbuf + (size_t)bh * 65536 + grp * 512;

  uint4 kr[2], vr[2];
#define LOADK(kt)                                                                  \
  _Pragma("unroll") for (int i = 0; i < 2; ++i) {                                  \
    int j = tg + 256 * i;                                                          \
    kr[i] = *(const uint4*)&kp0[((size_t)(kt)*64 + (j >> 3)) * 64 + (j & 7) * 8];  \
  }
#define LOADV(kt)                                                                  \
  _Pragma("unroll") for (int i = 0; i < 2; ++i) {                                  \
    int j = tg + 256 * i;                                                          \
    vr[i] = *(const uint4*)&vp0[(size_t)(j >> 3) * 1024 + (kt)*64 + (j & 7) * 8];  \
  }
#define WRITEK(bi)                                                                 \
  _Pragma("unroll") for (int i = 0; i < 2; ++i) {                                  \
    int j = tg + 256 * i;                                                          \
    int row = j >> 3, off = j & 7;                                                 \
    *(uint4*)((char*)kb_ + (bi)*8192 + row * 128 + ((off * 16) ^ ((row & 7) << 4))) = kr[i]; \
  }
#define WRITEV(bi)                                                                 \
  _Pragma("unroll") for (int i = 0; i < 2; ++i) {                                  \
    int j = tg + 256 * i;                                                          \
    int d = j >> 3, g = j & 7;                                                     \
    int base = (g >> 2) * 64 + (g & 1) * 32 + ((g >> 1) & 1) * 8;                  \
    char* vb = (char*)vb_ + (bi)*8192 + d * 128;                                   \
    uint2 lo = {vr[i].x, vr[i].y}, hi = {vr[i].z, vr[i].w};                        \
    *(uint2*)(vb + ((base) ^ ((d & 7) << 4))) = lo;                                \
    *(uint2*)(vb + ((base + 16) ^ ((d & 7) << 4))) = hi;                           \
  }

  f32x4 oacc[2][4] = {};
  float mrun[2] = {-3e38f, -3e38f}, lrun[2] = {0.f, 0.f};
  const float kSL2E = 0.125f * LOG2E;
  int cur = 0;

  LOADK(0) LOADV(0) WRITEK(0) WRITEV(0)
  __syncthreads();

  for (int kt = 0; kt < 8; ++kt) {
    if (kt < 7) { LOADK(kt + 1) LOADV(kt + 1) }

    f32x4 sT[2][4];
    __builtin_amdgcn_s_setprio(1);
#pragma unroll
    for (int nf = 0; nf < 4; ++nf) {
      const int n = nf * 16 + col;
      const char* kb = (const char*)kb_ + cur * 8192 + n * 128;
      const int sw = (n & 7) << 4;
      bf16x8 bk0 = *(const bf16x8*)(kb + ((rg * 16) ^ sw));
      bf16x8 bk1 = *(const bf16x8*)(kb + ((64 + rg * 16) ^ sw));
#pragma unroll
      for (int mf = 0; mf < 2; ++mf) {
        f32x4 z = {};
        z = MFMA16(bk0, aq[mf][0], z);
        sT[mf][nf] = MFMA16(bk1, aq[mf][1], z);
      }
    }
    __builtin_amdgcn_s_setprio(0);

    unsigned pk[2][4][2];
#pragma unroll
    for (int mf = 0; mf < 2; ++mf) {
      f32x4 mv = sT[mf][0];
#pragma unroll
      for (int nf = 1; nf < 4; ++nf)
#pragma unroll
        for (int r = 0; r < 4; ++r) mv[r] = fmaxf(mv[r], sT[mf][nf][r]);
      float mx = fmaxf(fmaxf(mv[0], mv[1]), fmaxf(mv[2], mv[3]));
      if (!__all(mx * 0.125f <= mrun[mf] + 8.f)) {
        float mxr = fmaxf(mx, __shfl_xor(mx, 16));
        mxr = fmaxf(mxr, __shfl_xor(mxr, 32));
        const float pmax = mxr * 0.125f;
        const float mnew = fmaxf(mrun[mf], pmax);
        const float alpha = __builtin_amdgcn_exp2f((mrun[mf] - mnew) * LOG2E);
        mrun[mf] = mnew;
        lrun[mf] *= alpha;
#pragma unroll
        for (int df = 0; df < 4; ++df) oacc[mf][df] *= alpha;
      }
      const float nege = mrun[mf] * LOG2E;
      float psum = 0.f;
#pragma unroll
      for (int nf = 0; nf < 4; ++nf) {
        float p0 = __builtin_amdgcn_exp2f(fmaf(sT[mf][nf][0], kSL2E, -nege));
        float p1 = __builtin_amdgcn_exp2f(fmaf(sT[mf][nf][1], kSL2E, -nege));
        float p2 = __builtin_amdgcn_exp2f(fmaf(sT[mf][nf][2], kSL2E, -nege));
        float p3 = __builtin_amdgcn_exp2f(fmaf(sT[mf][nf][3], kSL2E, -nege));
        psum += (p0 + p1) + (p2 + p3);
        pk[mf][nf][0] = cvtpk(p0, p1);
        pk[mf][nf][1] = cvtpk(p2, p3);
      }
      lrun[mf] += psum;
    }

    __builtin_amdgcn_s_setprio(1);
#pragma unroll
    for (int kc = 0; kc < 2; ++kc) {
      bf16x8 pb[2];
#pragma unroll
      for (int mf = 0; mf < 2; ++mf) {
        u32x4 pbu = {pk[mf][2 * kc][0], pk[mf][2 * kc][1], pk[mf][2 * kc + 1][0],
                     pk[mf][2 * kc + 1][1]};
        pb[mf] = __builtin_bit_cast(bf16x8, pbu);
      }
#pragma unroll
      for (int df = 0; df < 4; ++df) {
        const int d = df * 16 + col;
        bf16x8 av = *(const bf16x8*)((const char*)vb_ + cur * 8192 + d * 128 +
                                     ((kc * 64 + rg * 16) ^ ((d & 7) << 4)));
#pragma unroll
        for (int mf = 0; mf < 2; ++mf) oacc[mf][df] = MFMA16(av, pb[mf], oacc[mf][df]);
      }
    }
    __builtin_amdgcn_s_setprio(0);

    if (kt < 7) { WRITEK(cur ^ 1) WRITEV(cur ^ 1) }
    __syncthreads();
    cur ^= 1;
  }

#pragma unroll
  for (int mf = 0; mf < 2; ++mf) {
    float l = lrun[mf];
    l += __shfl_xor(l, 16);
    l += __shfl_xor(l, 32);
    lrun[mf] = l;
  }

  f32x4* o_lds = (f32x4*)smem;
  float* ml_lds = (float*)(smem + 32768);
  short* o16 = (short*)(smem + 36864);
  if (grp == 1) {
#pragma unroll
    for (int mf = 0; mf < 2; ++mf) {
#pragma unroll
      for (int df = 0; df < 4; ++df)
        o_lds[(((wq * 2 + mf) * 4) + df) * 64 + lane] = oacc[mf][df];
      ml_lds[((wq * 2 + mf) * 64 + lane) * 2] = mrun[mf];
      ml_lds[((wq * 2 + mf) * 64 + lane) * 2 + 1] = lrun[mf];
    }
  }
  __syncthreads();
  if (grp == 0) {
#pragma unroll
    for (int mf = 0; mf < 2; ++mf) {
      const float m1 = ml_lds[((wq * 2 + mf) * 64 + lane) * 2];
      const float l1 = ml_lds[((wq * 2 + mf) * 64 + lane) * 2 + 1];
      const float m = fmaxf(mrun[mf], m1);
      const float a0 = __builtin_amdgcn_exp2f((mrun[mf] - m) * LOG2E);
      const float a1 = __builtin_amdgcn_exp2f((m1 - m) * LOG2E);
      const float rl = 1.f / (lrun[mf] * a0 + l1 * a1);
      const int qq = wq * 32 + mf * 16 + col;
#pragma unroll
      for (int df = 0; df < 4; ++df) {
        f32x4 o1 = o_lds[(((wq * 2 + mf) * 4) + df) * 64 + lane];
        short4v pkv;
#pragma unroll
        for (int r = 0; r < 4; ++r)
          pkv[r] = f2bf((oacc[mf][df][r] * a0 + o1[r] * a1) * rl);
        const int cd = df * 2 + (rg >> 1);
        *(short4v*)&o16[qq * 64 + ((cd ^ (qq & 7)) << 3) + (rg & 1) * 4] = pkv;
      }
    }
  }
  __syncthreads();
#pragma unroll
  for (int p = 0; p < 2; ++p) {
    const int idx = p * 512 + t;
    const int kd = idx & 7, qq = idx >> 3;
    uint4 vvv = *(const uint4*)&o16[qq * 64 + ((kd ^ (qq & 7)) << 3)];
    *(uint4*)&ao[((size_t)b * 1024 + qt * 128 + qq) * 512 + h * 64 + kd * 8] = vvv;
  }
#undef LOADK
#undef LOADV
#undef WRITEK
#undef WRITEV
}

// ---------------------------------------------------------------------------
// Proj GEMM + bias + fp32 residual — race-free 2-deep pipeline (R17/R18).
// ---------------------------------------------------------------------------
__global__ __launch_bounds__(256) void proj_gemm(const short* __restrict__ W,
                                                 const short* __restrict__ ao,
                                                 const float* __restrict__ bias,
                                                 const float* __restrict__ x,
                                                 float* __restrict__ out) {
  __shared__ short a_sm[3][64 * 32];
  __shared__ short b_sm[3][128 * 32];
  const int t = threadIdx.x;
  const int lane = t & 63, w = t >> 6;
  const int nbase = blockIdx.x * 128;
  const int mbase = blockIdx.y * 64;
  const int b = blockIdx.z;
  const short* Asrc = W + (size_t)mbase * 512;
  const short* Bsrc = ao + (size_t)b * 1024 * 512 + (size_t)nbase * 512;

  const int j0 = t, j1 = t + 256;
  const int r0 = j0 >> 2, c0 = ((j0 & 3) ^ ((j0 >> 3) & 3)) * 8;
  const int r1 = j1 >> 2, c1 = ((j1 & 3) ^ ((j1 >> 3) & 3)) * 8;

#define STAGE(bi, kt)                                                 \
  {                                                                   \
    const int k0s = (kt) * 32;                                        \
    g2l16(&a_sm[bi][j0 * 8], Asrc + (size_t)r0 * 512 + k0s + c0);     \
    g2l16(&b_sm[bi][j0 * 8], Bsrc + (size_t)r0 * 512 + k0s + c0);     \
    g2l16(&b_sm[bi][j1 * 8], Bsrc + (size_t)r1 * 512 + k0s + c1);     \
  }

  const int wm = (w >> 1) * 32, wn = (w & 1) * 64;
  const int col = lane & 15, rg = lane >> 4;

  f32x4 acc[2][4] = {};

  STAGE(0, 0)
  STAGE(1, 1)

  for (int kt = 0; kt < 16; ++kt) {
    const int cur = kt % 3;
    if (kt < 15) {
      asm volatile("s_waitcnt vmcnt(3)" ::: "memory");
    } else {
      asm volatile("s_waitcnt vmcnt(0)" ::: "memory");
    }
    __builtin_amdgcn_s_barrier();
    __builtin_amdgcn_sched_barrier(0);
    if (kt < 14) STAGE((kt + 2) % 3, kt + 2)

    bf16x8 af[2], bfr[4];
#pragma unroll
    for (int mf = 0; mf < 2; ++mf) {
      const int row = wm + mf * 16 + col;
      af[mf] = *(const bf16x8*)&a_sm[cur][row * 32 + ((rg ^ ((row >> 1) & 3)) * 8)];
    }
#pragma unroll
    for (int nf = 0; nf < 4; ++nf) {
      const int row = wn + nf * 16 + col;
      bfr[nf] = *(const bf16x8*)&b_sm[cur][row * 32 + ((rg ^ ((row >> 1) & 3)) * 8)];
    }
    __builtin_amdgcn_s_setprio(1);
#pragma unroll
    for (int mf = 0; mf < 2; ++mf)
#pragma unroll
      for (int nf = 0; nf < 4; ++nf)
        acc[mf][nf] = MFMA16(af[mf], bfr[nf], acc[mf][nf]);
    __builtin_amdgcn_s_setprio(0);
  }
#undef STAGE

  for (int mf = 0; mf < 2; ++mf) {
    const int o0 = mbase + wm + mf * 16 + rg * 4;
    float b4[4];
    for (int r = 0; r < 4; ++r) b4[r] = bias[o0 + r];
    for (int nf = 0; nf < 4; ++nf) {
      const int n = nbase + wn + nf * 16 + col;
      for (int r = 0; r < 4; ++r) {
        size_t idx = ((size_t)b * 512 + o0 + r) * 1024 + n;
        out[idx] = x[idx] + acc[mf][nf][r] + b4[r];
      }
    }
  }
}

// ---------------------------------------------------------------------------
extern "C" void kernel_launch(void* const* d_in, const int* in_sizes, int n_in,
                              void* d_out, int out_size, void* d_ws, size_t ws_size,
                              hipStream_t stream) {
  const float* x = (const float*)d_in[0];
  const float* gamma = (const float*)d_in[1];
  const float* beta = (const float*)d_in[2];
  const float* w_qkv = (const float*)d_in[3];
  const float* b_qkv = (const float*)d_in[4];
  const float* w_proj = (const float*)d_in[5];
  const float* b_proj = (const float*)d_in[6];
  float* out = (float*)d_out;

  char* ws = (char*)d_ws;
  float* sa = (float*)(ws);                    // 16 KB  [8][512] f32
  float* sb = (float*)(ws + 16384);            // 16 KB
  short* wqkv_b = (short*)(ws + 8388608);      // 1.5 MB
  short* wproj_b = (short*)(ws + 9961472);     // 0.5 MB
  short* qbuf = (short*)(ws + 10485760);       // 8 MB   (BH,N,d)
  short* kbuf = (short*)(ws + 18874368);       // 8 MB   (BH,N,d)
  short* vtbuf = (short*)(ws + 27262976);      // 8 MB   (BH,d,N)
  short* aobuf = (short*)(ws + 35651584);      // 8 MB   (B,N,C)

  gn_stats<<<dim3(256), dim3(256), 0, stream>>>(x, gamma, beta, sa, sb);
  f2bf2_kernel<<<dim3(1024), dim3(256), 0, stream>>>(w_qkv, wqkv_b, 196608, w_proj,
                                                     wproj_b);
  qkv_fused<<<dim3(8, 12, 8), dim3(512), 0, stream>>>(x, sa, sb, wqkv_b, b_qkv, qbuf,
                                                      kbuf, vtbuf);
  attn_kernel<<<dim3(64, 8), dim3(512), 0, stream>>>(qbuf, kbuf, vtbuf, aobuf);
  proj_gemm<<<dim3(8, 8, 8), dim3(256), 0, stream>>>(wproj_b, aobuf, b_proj, x, out);
}

// Round 21
// 72.830 us; speedup vs baseline: 1.2352x; 1.2352x over previous
//
#include <hip/hip_runtime.h>

#define LOG2E 1.4426950408889634f

typedef short bf16x8 __attribute__((ext_vector_type(8)));
typedef short short4v __attribute__((ext_vector_type(4)));
typedef float f32x4 __attribute__((ext_vector_type(4)));
typedef _Float16 half4v __attribute__((ext_vector_type(4)));
typedef unsigned u32x4 __attribute__((ext_vector_type(4)));
typedef unsigned __attribute__((address_space(1))) u32g;
typedef unsigned __attribute__((address_space(3))) u32l;

#define MFMA16(a, b, c) __builtin_amdgcn_mfma_f32_16x16x32_bf16((a), (b), (c), 0, 0, 0)

__device__ __forceinline__ short f2bf(float f) {
  unsigned u = __builtin_bit_cast(unsigned, f);
  u += 0x7FFFu + ((u >> 16) & 1u);
  return (short)(u >> 16);
}

__device__ __forceinline__ unsigned cvtpk(float lo, float hi) {
  unsigned r;
  asm("v_cvt_pk_bf16_f32 %0, %1, %2" : "=v"(r) : "v"(lo), "v"(hi));
  return r;
}

__device__ __forceinline__ void g2l16(void* lds, const void* g) {
  __builtin_amdgcn_global_load_lds((u32g*)const_cast<void*>(g), (u32l*)lds, 16, 0, 0);
}

// ---------------------------------------------------------------------------
// GroupNorm: x (B,512,1024) f32 -> xn_t (B,1024,512) bf16
// ---------------------------------------------------------------------------
__global__ __launch_bounds__(256) void gn_kernel(const float* __restrict__ x,
                                                 const float* __restrict__ gamma,
                                                 const float* __restrict__ beta,
                                                 short* __restrict__ xn_t) {
  __shared__ _Float16 xs[16 * 1024];  // 32 KB, row = channel, swizzled
  __shared__ float red[8];
  const int bg = blockIdx.x;
  const int b = bg >> 5, g = bg & 31;
  const int t = threadIdx.x;
  const float4* gx4 = (const float4*)(x + (size_t)(b * 512 + g * 16) * 1024);
  float s1 = 0.f, s2 = 0.f;
  for (int i = 0; i < 16; ++i) {
    float4 v = gx4[t + 256 * i];
    s1 += (v.x + v.y) + (v.z + v.w);
    s2 += (v.x * v.x + v.y * v.y) + (v.z * v.z + v.w * v.w);
    half4v pk = {(_Float16)v.x, (_Float16)v.y, (_Float16)v.z, (_Float16)v.w};
    *(half4v*)((char*)xs + i * 2048 + ((8 * t) ^ ((i & 7) << 4))) = pk;
  }
  for (int m = 1; m < 64; m <<= 1) {
    s1 += __shfl_xor(s1, m);
    s2 += __shfl_xor(s2, m);
  }
  if ((t & 63) == 0) {
    red[(t >> 6) * 2] = s1;
    red[(t >> 6) * 2 + 1] = s2;
  }
  __syncthreads();
  s1 = (red[0] + red[2]) + (red[4] + red[6]);
  s2 = (red[1] + red[3]) + (red[5] + red[7]);
  const float mean = s1 * (1.f / 16384.f);
  const float var = s2 * (1.f / 16384.f) - mean * mean;
  const float rstd = rsqrtf(var + 1e-6f);
  const int ci = t & 15;
  const float ga = gamma[g * 16 + ci] * rstd;
  const float be = beta[g * 16 + ci] - mean * ga;
  short* dst = xn_t + (size_t)b * 1024 * 512 + g * 16 + ci;
  const int sw = (ci & 7) << 4;
  for (int i = 0; i < 64; ++i) {
    int n = (t >> 4) + 16 * i;
    float v = (float)*(const _Float16*)((const char*)xs + ci * 2048 + ((2 * n) ^ sw));
    dst[(size_t)n * 512] = f2bf(fmaf(v, ga, be));
  }
}

// ---------------------------------------------------------------------------
__global__ __launch_bounds__(256) void f2bf2_kernel(const float* __restrict__ s1,
                                                    short* __restrict__ d1, int n1,
                                                    const float* __restrict__ s2,
                                                    short* __restrict__ d2) {
  int i = blockIdx.x * 256 + threadIdx.x;
  const float* s = (i < n1) ? s1 : s2;
  short* d = (i < n1) ? d1 : d2;
  int j = (i < n1) ? i : i - n1;
  float4 v = ((const float4*)s)[j];
  short4v o = {f2bf(v.x), f2bf(v.y), f2bf(v.z), f2bf(v.w)};
  *(short4v*)(d + (size_t)j * 4) = o;
}

// ---------------------------------------------------------------------------
// QKV GEMM — 128x128 tile, 512 thr / 8 waves, race-free 2-deep pipeline,
// coalesced LDS-transpose epilogue (R18 best-known configuration).
// ---------------------------------------------------------------------------
__global__ __launch_bounds__(512, 6) void qkv_gemm(const short* __restrict__ W,
                                                   const short* __restrict__ xn,
                                                   const float* __restrict__ bias,
                                                   short* __restrict__ qbuf,
                                                   short* __restrict__ kbuf,
                                                   short* __restrict__ vtbuf) {
  __shared__ short a_sm[3][128 * 32];
  __shared__ short b_sm[3][128 * 32];
  const int t = threadIdx.x;
  const int lane = t & 63, w = t >> 6;
  const int nbase = blockIdx.x * 128;
  const int mbase = blockIdx.y * 128;
  const int b = blockIdx.z;
  const short* Asrc = W + (size_t)mbase * 512;
  const short* Bsrc = xn + (size_t)b * 1024 * 512 + (size_t)nbase * 512;

  const int j = t;
  const int r = j >> 2, c = ((j & 3) ^ ((j >> 3) & 3)) * 8;

#define STAGE(bi, kt)                                              \
  {                                                                \
    const int k0s = (kt) * 32;                                     \
    g2l16(&a_sm[bi][j * 8], Asrc + (size_t)r * 512 + k0s + c);     \
    g2l16(&b_sm[bi][j * 8], Bsrc + (size_t)r * 512 + k0s + c);     \
  }

  const int wm = (w >> 2) * 64, wn = (w & 3) * 32;
  const int col = lane & 15, rg = lane >> 4;

  f32x4 acc[4][2] = {};

  STAGE(0, 0)
  STAGE(1, 1)

  for (int kt = 0; kt < 16; ++kt) {
    const int cur = kt % 3;
    if (kt < 15) {
      asm volatile("s_waitcnt vmcnt(2)" ::: "memory");
    } else {
      asm volatile("s_waitcnt vmcnt(0)" ::: "memory");
    }
    __builtin_amdgcn_s_barrier();
    __builtin_amdgcn_sched_barrier(0);
    if (kt < 14) STAGE((kt + 2) % 3, kt + 2)

    bf16x8 af[4], bfr[2];
#pragma unroll
    for (int mf = 0; mf < 4; ++mf) {
      const int row = wm + mf * 16 + col;
      af[mf] = *(const bf16x8*)&a_sm[cur][row * 32 + ((rg ^ ((row >> 1) & 3)) * 8)];
    }
#pragma unroll
    for (int nf = 0; nf < 2; ++nf) {
      const int row = wn + nf * 16 + col;
      bfr[nf] = *(const bf16x8*)&b_sm[cur][row * 32 + ((rg ^ ((row >> 1) & 3)) * 8)];
    }
    __builtin_amdgcn_s_setprio(1);
#pragma unroll
    for (int mf = 0; mf < 4; ++mf)
#pragma unroll
      for (int nf = 0; nf < 2; ++nf)
        acc[mf][nf] = MFMA16(af[mf], bfr[nf], acc[mf][nf]);
    __builtin_amdgcn_s_setprio(0);
  }
#undef STAGE

  // ---- coalesced epilogue via LDS transpose (32 KB overlay on a_sm) ----
  __syncthreads();
  short* e_sm = (short*)a_sm;
  const int section = mbase >> 9;
  const int bh0 = b * 8 + ((mbase >> 6) & 7);

  if (section < 2) {
#pragma unroll
    for (int mf = 0; mf < 4; ++mf) {
      const int o0 = mbase + wm + mf * 16 + rg * 4;
      float b4[4];
#pragma unroll
      for (int r2 = 0; r2 < 4; ++r2) b4[r2] = bias[o0 + r2];
      const int mloc0 = wm + mf * 16 + rg * 4;
#pragma unroll
      for (int nf = 0; nf < 2; ++nf) {
        const int nn = wn + nf * 16 + col;
#pragma unroll
        for (int r2 = 0; r2 < 4; ++r2) {
          const int m = mloc0 + r2;
          e_sm[nn * 128 + (((m >> 3) ^ (nn & 7)) << 3) + (m & 7)] =
              f2bf(acc[mf][nf][r2] + b4[r2]);
        }
      }
    }
    __syncthreads();
    short* dst = (section == 0) ? qbuf : kbuf;
#pragma unroll
    for (int p = 0; p < 4; ++p) {
      const int idx = p * 512 + t;
      const int kd = idx & 7, rr = idx >> 3;
      const int hh = rr >> 7, nn = rr & 127;
      const int cm = hh * 8 + kd;
      uint4 vvv = *(const uint4*)&e_sm[nn * 128 + ((cm ^ (nn & 7)) << 3)];
      *(uint4*)&dst[((size_t)(bh0 + hh) * 1024 + nbase + nn) * 64 + kd * 8] = vvv;
    }
  } else {
#pragma unroll
    for (int mf = 0; mf < 4; ++mf) {
      const int o0 = mbase + wm + mf * 16 + rg * 4;
      float b4[4];
#pragma unroll
      for (int r2 = 0; r2 < 4; ++r2) b4[r2] = bias[o0 + r2];
      const int mloc0 = wm + mf * 16 + rg * 4;
#pragma unroll
      for (int nf = 0; nf < 2; ++nf) {
        const int nn = wn + nf * 16 + col;
        const int cn = nn >> 3;
#pragma unroll
        for (int r2 = 0; r2 < 4; ++r2) {
          const int m = mloc0 + r2;
          e_sm[m * 128 + ((cn ^ (m & 7)) << 3) + (nn & 7)] =
              f2bf(acc[mf][nf][r2] + b4[r2]);
        }
      }
    }
    __syncthreads();
#pragma unroll
    for (int p = 0; p < 4; ++p) {
      const int idx = p * 512 + t;
      const int kd = idx & 15, m = idx >> 4;
      const int hh = m >> 6, dd = m & 63;
      uint4 vvv = *(const uint4*)&e_sm[m * 128 + ((kd ^ (m & 7)) << 3)];
      *(uint4*)&vtbuf[((size_t)(bh0 + hh) * 64 + dd) * 1024 + nbase + kd * 8] = vvv;
    }
  }
}

// ---------------------------------------------------------------------------
// Flash attention (R18 — lane-local softmax, kv-split, coalesced output).
// ---------------------------------------------------------------------------
__global__ __launch_bounds__(512, 4) void attn_kernel(const short* __restrict__ qbuf,
                                                      const short* __restrict__ kbuf,
                                                      const short* __restrict__ vtbuf,
                                                      short* __restrict__ ao) {
  __shared__ char smem[65536];
  const int t = threadIdx.x, lane = t & 63, w = t >> 6;
  const int col = lane & 15, rg = lane >> 4;
  const int grp = w >> 2, wq = w & 3;
  const int tg = t & 255;
  const int bh = blockIdx.x, qt = blockIdx.y;
  const int b = bh >> 3, h = bh & 7;
  const int qbase = qt * 128 + wq * 32;

  short* kb_ = (short*)(smem + grp * 32768);
  short* vb_ = (short*)(smem + grp * 32768 + 16384);

  bf16x8 aq[2][2];
  {
    const short* qp = qbuf + ((size_t)bh * 1024 + qbase) * 64;
#pragma unroll
    for (int mf = 0; mf < 2; ++mf)
#pragma unroll
      for (int kc = 0; kc < 2; ++kc)
        aq[mf][kc] = *(const bf16x8*)&qp[(mf * 16 + col) * 64 + kc * 32 + rg * 8];
  }

  const short* kp0 = kbuf + (size_t)bh * 65536 + grp * 32768;
  const short* vp0 = vtbuf + (size_t)bh * 65536 + grp * 512;

  uint4 kr[2], vr[2];
#define LOADK(kt)                                                                  \
  _Pragma("unroll") for (int i = 0; i < 2; ++i) {                                  \
    int j = tg + 256 * i;                                                          \
    kr[i] = *(const uint4*)&kp0[((size_t)(kt)*64 + (j >> 3)) * 64 + (j & 7) * 8];  \
  }
#define LOADV(kt)                                                                  \
  _Pragma("unroll") for (int i = 0; i < 2; ++i) {                                  \
    int j = tg + 256 * i;                                                          \
    vr[i] = *(const uint4*)&vp0[(size_t)(j >> 3) * 1024 + (kt)*64 + (j & 7) * 8];  \
  }
#define WRITEK(bi)                                                                 \
  _Pragma("unroll") for (int i = 0; i < 2; ++i) {                                  \
    int j = tg + 256 * i;                                                          \
    int row = j >> 3, off = j & 7;                                                 \
    *(uint4*)((char*)kb_ + (bi)*8192 + row * 128 + ((off * 16) ^ ((row & 7) << 4))) = kr[i]; \
  }
#define WRITEV(bi)                                                                 \
  _Pragma("unroll") for (int i = 0; i < 2; ++i) {                                  \
    int j = tg + 256 * i;                                                          \
    int d = j >> 3, g = j & 7;                                                     \
    int base = (g >> 2) * 64 + (g & 1) * 32 + ((g >> 1) & 1) * 8;                  \
    char* vb = (char*)vb_ + (bi)*8192 + d * 128;                                   \
    uint2 lo = {vr[i].x, vr[i].y}, hi = {vr[i].z, vr[i].w};                        \
    *(uint2*)(vb + ((base) ^ ((d & 7) << 4))) = lo;                                \
    *(uint2*)(vb + ((base + 16) ^ ((d & 7) << 4))) = hi;                           \
  }

  f32x4 oacc[2][4] = {};
  float mrun[2] = {-3e38f, -3e38f}, lrun[2] = {0.f, 0.f};
  const float kSL2E = 0.125f * LOG2E;
  int cur = 0;

  LOADK(0) LOADV(0) WRITEK(0) WRITEV(0)
  __syncthreads();

  for (int kt = 0; kt < 8; ++kt) {
    if (kt < 7) { LOADK(kt + 1) LOADV(kt + 1) }

    f32x4 sT[2][4];
    __builtin_amdgcn_s_setprio(1);
#pragma unroll
    for (int nf = 0; nf < 4; ++nf) {
      const int n = nf * 16 + col;
      const char* kb = (const char*)kb_ + cur * 8192 + n * 128;
      const int sw = (n & 7) << 4;
      bf16x8 bk0 = *(const bf16x8*)(kb + ((rg * 16) ^ sw));
      bf16x8 bk1 = *(const bf16x8*)(kb + ((64 + rg * 16) ^ sw));
#pragma unroll
      for (int mf = 0; mf < 2; ++mf) {
        f32x4 z = {};
        z = MFMA16(bk0, aq[mf][0], z);
        sT[mf][nf] = MFMA16(bk1, aq[mf][1], z);
      }
    }
    __builtin_amdgcn_s_setprio(0);

    unsigned pk[2][4][2];
#pragma unroll
    for (int mf = 0; mf < 2; ++mf) {
      f32x4 mv = sT[mf][0];
#pragma unroll
      for (int nf = 1; nf < 4; ++nf)
#pragma unroll
        for (int r = 0; r < 4; ++r) mv[r] = fmaxf(mv[r], sT[mf][nf][r]);
      float mx = fmaxf(fmaxf(mv[0], mv[1]), fmaxf(mv[2], mv[3]));
      if (!__all(mx * 0.125f <= mrun[mf] + 8.f)) {
        float mxr = fmaxf(mx, __shfl_xor(mx, 16));
        mxr = fmaxf(mxr, __shfl_xor(mxr, 32));
        const float pmax = mxr * 0.125f;
        const float mnew = fmaxf(mrun[mf], pmax);
        const float alpha = __builtin_amdgcn_exp2f((mrun[mf] - mnew) * LOG2E);
        mrun[mf] = mnew;
        lrun[mf] *= alpha;
#pragma unroll
        for (int df = 0; df < 4; ++df) oacc[mf][df] *= alpha;
      }
      const float nege = mrun[mf] * LOG2E;
      float psum = 0.f;
#pragma unroll
      for (int nf = 0; nf < 4; ++nf) {
        float p0 = __builtin_amdgcn_exp2f(fmaf(sT[mf][nf][0], kSL2E, -nege));
        float p1 = __builtin_amdgcn_exp2f(fmaf(sT[mf][nf][1], kSL2E, -nege));
        float p2 = __builtin_amdgcn_exp2f(fmaf(sT[mf][nf][2], kSL2E, -nege));
        float p3 = __builtin_amdgcn_exp2f(fmaf(sT[mf][nf][3], kSL2E, -nege));
        psum += (p0 + p1) + (p2 + p3);
        pk[mf][nf][0] = cvtpk(p0, p1);
        pk[mf][nf][1] = cvtpk(p2, p3);
      }
      lrun[mf] += psum;
    }

    __builtin_amdgcn_s_setprio(1);
#pragma unroll
    for (int kc = 0; kc < 2; ++kc) {
      bf16x8 pb[2];
#pragma unroll
      for (int mf = 0; mf < 2; ++mf) {
        u32x4 pbu = {pk[mf][2 * kc][0], pk[mf][2 * kc][1], pk[mf][2 * kc + 1][0],
                     pk[mf][2 * kc + 1][1]};
        pb[mf] = __builtin_bit_cast(bf16x8, pbu);
      }
#pragma unroll
      for (int df = 0; df < 4; ++df) {
        const int d = df * 16 + col;
        bf16x8 av = *(const bf16x8*)((const char*)vb_ + cur * 8192 + d * 128 +
                                     ((kc * 64 + rg * 16) ^ ((d & 7) << 4)));
#pragma unroll
        for (int mf = 0; mf < 2; ++mf) oacc[mf][df] = MFMA16(av, pb[mf], oacc[mf][df]);
      }
    }
    __builtin_amdgcn_s_setprio(0);

    if (kt < 7) { WRITEK(cur ^ 1) WRITEV(cur ^ 1) }
    __syncthreads();
    cur ^= 1;
  }

#pragma unroll
  for (int mf = 0; mf < 2; ++mf) {
    float l = lrun[mf];
    l += __shfl_xor(l, 16);
    l += __shfl_xor(l, 32);
    lrun[mf] = l;
  }

  f32x4* o_lds = (f32x4*)smem;
  float* ml_lds = (float*)(smem + 32768);
  short* o16 = (short*)(smem + 36864);
  if (grp == 1) {
#pragma unroll
    for (int mf = 0; mf < 2; ++mf) {
#pragma unroll
      for (int df = 0; df < 4; ++df)
        o_lds[(((wq * 2 + mf) * 4) + df) * 64 + lane] = oacc[mf][df];
      ml_lds[((wq * 2 + mf) * 64 + lane) * 2] = mrun[mf];
      ml_lds[((wq * 2 + mf) * 64 + lane) * 2 + 1] = lrun[mf];
    }
  }
  __syncthreads();
  if (grp == 0) {
#pragma unroll
    for (int mf = 0; mf < 2; ++mf) {
      const float m1 = ml_lds[((wq * 2 + mf) * 64 + lane) * 2];
      const float l1 = ml_lds[((wq * 2 + mf) * 64 + lane) * 2 + 1];
      const float m = fmaxf(mrun[mf], m1);
      const float a0 = __builtin_amdgcn_exp2f((mrun[mf] - m) * LOG2E);
      const float a1 = __builtin_amdgcn_exp2f((m1 - m) * LOG2E);
      const float rl = 1.f / (lrun[mf] * a0 + l1 * a1);
      const int qq = wq * 32 + mf * 16 + col;
#pragma unroll
      for (int df = 0; df < 4; ++df) {
        f32x4 o1 = o_lds[(((wq * 2 + mf) * 4) + df) * 64 + lane];
        short4v pkv;
#pragma unroll
        for (int r = 0; r < 4; ++r)
          pkv[r] = f2bf((oacc[mf][df][r] * a0 + o1[r] * a1) * rl);
        const int cd = df * 2 + (rg >> 1);
        *(short4v*)&o16[qq * 64 + ((cd ^ (qq & 7)) << 3) + (rg & 1) * 4] = pkv;
      }
    }
  }
  __syncthreads();
#pragma unroll
  for (int p = 0; p < 2; ++p) {
    const int idx = p * 512 + t;
    const int kd = idx & 7, qq = idx >> 3;
    uint4 vvv = *(const uint4*)&o16[qq * 64 + ((kd ^ (qq & 7)) << 3)];
    *(uint4*)&ao[((size_t)b * 1024 + qt * 128 + qq) * 512 + h * 64 + kd * 8] = vvv;
  }
#undef LOADK
#undef LOADV
#undef WRITEK
#undef WRITEV
}

// ---------------------------------------------------------------------------
// Proj GEMM + bias + fp32 residual — race-free 2-deep pipeline (R17/R18).
// ---------------------------------------------------------------------------
__global__ __launch_bounds__(256) void proj_gemm(const short* __restrict__ W,
                                                 const short* __restrict__ ao,
                                                 const float* __restrict__ bias,
                                                 const float* __restrict__ x,
                                                 float* __restrict__ out) {
  __shared__ short a_sm[3][64 * 32];
  __shared__ short b_sm[3][128 * 32];
  const int t = threadIdx.x;
  const int lane = t & 63, w = t >> 6;
  const int nbase = blockIdx.x * 128;
  const int mbase = blockIdx.y * 64;
  const int b = blockIdx.z;
  const short* Asrc = W + (size_t)mbase * 512;
  const short* Bsrc = ao + (size_t)b * 1024 * 512 + (size_t)nbase * 512;

  const int j0 = t, j1 = t + 256;
  const int r0 = j0 >> 2, c0 = ((j0 & 3) ^ ((j0 >> 3) & 3)) * 8;
  const int r1 = j1 >> 2, c1 = ((j1 & 3) ^ ((j1 >> 3) & 3)) * 8;

#define STAGE(bi, kt)                                                 \
  {                                                                   \
    const int k0s = (kt) * 32;                                        \
    g2l16(&a_sm[bi][j0 * 8], Asrc + (size_t)r0 * 512 + k0s + c0);     \
    g2l16(&b_sm[bi][j0 * 8], Bsrc + (size_t)r0 * 512 + k0s + c0);     \
    g2l16(&b_sm[bi][j1 * 8], Bsrc + (size_t)r1 * 512 + k0s + c1);     \
  }

  const int wm = (w >> 1) * 32, wn = (w & 1) * 64;
  const int col = lane & 15, rg = lane >> 4;

  f32x4 acc[2][4] = {};

  STAGE(0, 0)
  STAGE(1, 1)

  for (int kt = 0; kt < 16; ++kt) {
    const int cur = kt % 3;
    if (kt < 15) {
      asm volatile("s_waitcnt vmcnt(3)" ::: "memory");
    } else {
      asm volatile("s_waitcnt vmcnt(0)" ::: "memory");
    }
    __builtin_amdgcn_s_barrier();
    __builtin_amdgcn_sched_barrier(0);
    if (kt < 14) STAGE((kt + 2) % 3, kt + 2)

    bf16x8 af[2], bfr[4];
#pragma unroll
    for (int mf = 0; mf < 2; ++mf) {
      const int row = wm + mf * 16 + col;
      af[mf] = *(const bf16x8*)&a_sm[cur][row * 32 + ((rg ^ ((row >> 1) & 3)) * 8)];
    }
#pragma unroll
    for (int nf = 0; nf < 4; ++nf) {
      const int row = wn + nf * 16 + col;
      bfr[nf] = *(const bf16x8*)&b_sm[cur][row * 32 + ((rg ^ ((row >> 1) & 3)) * 8)];
    }
    __builtin_amdgcn_s_setprio(1);
#pragma unroll
    for (int mf = 0; mf < 2; ++mf)
#pragma unroll
      for (int nf = 0; nf < 4; ++nf)
        acc[mf][nf] = MFMA16(af[mf], bfr[nf], acc[mf][nf]);
    __builtin_amdgcn_s_setprio(0);
  }
#undef STAGE

  for (int mf = 0; mf < 2; ++mf) {
    const int o0 = mbase + wm + mf * 16 + rg * 4;
    float b4[4];
    for (int r = 0; r < 4; ++r) b4[r] = bias[o0 + r];
    for (int nf = 0; nf < 4; ++nf) {
      const int n = nbase + wn + nf * 16 + col;
      for (int r = 0; r < 4; ++r) {
        size_t idx = ((size_t)b * 512 + o0 + r) * 1024 + n;
        out[idx] = x[idx] + acc[mf][nf][r] + b4[r];
      }
    }
  }
}

// ---------------------------------------------------------------------------
extern "C" void kernel_launch(void* const* d_in, const int* in_sizes, int n_in,
                              void* d_out, int out_size, void* d_ws, size_t ws_size,
                              hipStream_t stream) {
  const float* x = (const float*)d_in[0];
  const float* gamma = (const float*)d_in[1];
  const float* beta = (const float*)d_in[2];
  const float* w_qkv = (const float*)d_in[3];
  const float* b_qkv = (const float*)d_in[4];
  const float* w_proj = (const float*)d_in[5];
  const float* b_proj = (const float*)d_in[6];
  float* out = (float*)d_out;

  char* ws = (char*)d_ws;
  short* xn_t = (short*)(ws);                  // 8 MB   (B,N,C) bf16
  short* wqkv_b = (short*)(ws + 8388608);      // 1.5 MB
  short* wproj_b = (short*)(ws + 9961472);     // 0.5 MB
  short* qbuf = (short*)(ws + 10485760);       // 8 MB   (BH,N,d)
  short* kbuf = (short*)(ws + 18874368);       // 8 MB   (BH,N,d)
  short* vtbuf = (short*)(ws + 27262976);      // 8 MB   (BH,d,N)
  short* aobuf = (short*)(ws + 35651584);      // 8 MB   (B,N,C)

  gn_kernel<<<dim3(256), dim3(256), 0, stream>>>(x, gamma, beta, xn_t);
  f2bf2_kernel<<<dim3(1024), dim3(256), 0, stream>>>(w_qkv, wqkv_b, 196608, w_proj,
                                                     wproj_b);
  qkv_gemm<<<dim3(8, 12, 8), dim3(512), 0, stream>>>(wqkv_b, xn_t, b_qkv, qbuf, kbuf,
                                                     vtbuf);
  attn_kernel<<<dim3(64, 8), dim3(512), 0, stream>>>(qbuf, kbuf, vtbuf, aobuf);
  proj_gemm<<<dim3(8, 8, 8), dim3(256), 0, stream>>>(wproj_b, aobuf, b_proj, x, out);
}